// Round 9
// baseline (471.866 us; speedup 1.0000x reference)
//
#include <hip/hip_runtime.h>
#include <hip/hip_fp16.h>
#include <math.h>

#define HD 64  // hidden dim H

typedef unsigned long long u64;
typedef _Float16 f16;
typedef _Float16 f16x8 __attribute__((ext_vector_type(8)));
typedef float f32x4 __attribute__((ext_vector_type(4)));

__device__ __forceinline__ u64 pack_rec(int src, float a0, float a1, float a2) {
    return (u64)(src & 0xFFFF)
         | ((u64)__half_as_ushort(__float2half(a0)) << 16)
         | ((u64)__half_as_ushort(__float2half(a1)) << 32)
         | ((u64)__half_as_ushort(__float2half(a2)) << 48);
}

// ---------------- init: cnt=0, zero gacc ----------------
__global__ void k_init(int* cnt, float* gacc, int N) {
    int i = blockIdx.x * blockDim.x + threadIdx.x;
    if (i < N) cnt[i] = 0;
    if (i < HD) gacc[i] = 0.f;
}

// ---------------- fused single ea pass: per-edge alphas -> recE (edge order),
// column-sum partials, in-degree histogram. Each block computes u = We@ae locally.
__global__ void k_pre(const int* __restrict__ ei, const float* __restrict__ ea,
                      const float* We1, const float* ae1,
                      const float* We2, const float* ae2,
                      const float* We3, const float* ae3,
                      int E, int FE, int* cnt, u64* __restrict__ recE,
                      float* __restrict__ partials) {
    extern __shared__ float lds[];
    float* sEA = lds;                         // 256*(FE+1)
    float* su = sEA + 256 * (FE + 1);         // 3*FE
    float* colacc = su + 3 * FE;              // 256*4
    int t = threadIdx.x;
    int ldE = FE + 1;

    if (t < 3 * FE) {
        int l = t / FE, f = t % FE;
        const float* We = (l == 0) ? We1 : (l == 1) ? We2 : We3;
        const float* ae = (l == 0) ? ae1 : (l == 1) ? ae2 : ae3;
        float s = 0.f;
        for (int hh = 0; hh < HD; ++hh) s += We[f * HD + hh] * ae[hh];
        su[t] = s;
    }

    const float4* ea4 = (const float4*)ea;
    int per_block = 64 * FE;  // 256 edges * FE/4 float4s
    size_t base4 = (size_t)blockIdx.x * per_block;
    size_t tot4 = (size_t)E * FE / 4;
    float4 acc = make_float4(0.f, 0.f, 0.f, 0.f);
    for (int i = t; i < per_block; i += 256) {
        size_t g4 = base4 + i;
        if (g4 < tot4) {
            float4 v = ea4[g4];
            acc.x += v.x; acc.y += v.y; acc.z += v.z; acc.w += v.w;
            int g = i * 4;
            int e_loc = g / FE, f = g % FE;
            float* p = &sEA[e_loc * ldE + f];
            p[0] = v.x; p[1] = v.y; p[2] = v.z; p[3] = v.w;
        }
    }
    colacc[t * 4 + 0] = acc.x; colacc[t * 4 + 1] = acc.y;
    colacc[t * 4 + 2] = acc.z; colacc[t * 4 + 3] = acc.w;

    int e = blockIdx.x * 256 + t;
    if (e < E) atomicAdd(&cnt[ei[E + e]], 1);
    __syncthreads();

    if (e < E) {
        float a0 = 0.f, a1 = 0.f, a2 = 0.f;
        const float* row = &sEA[t * ldE];
        for (int f = 0; f < FE; ++f) {
            float v = row[f];
            a0 += v * su[f];
            a1 += v * su[FE + f];
            a2 += v * su[2 * FE + f];
        }
        recE[e] = pack_rec(ei[e], a0, a1, a2);
    }
    if (t < 16) {
        int q = t >> 2, j = t & 3;  // feature = q*4 + j (thread with t%4==q holds quartet q)
        float s = 0.f;
        for (int k = 0; k < 64; ++k) s += colacc[(q + k * 4) * 4 + j];
        partials[blockIdx.x * 16 + (q * 4 + j)] = s;
    }
}

// ---------------- reduce partials -> mean_ea; sE[l] = mean_ea . u_l (u recomputed) ----------------
__global__ void k_u2(const float* __restrict__ partials, int NB,
                     const float* We1, const float* ae1,
                     const float* We2, const float* ae2,
                     const float* We3, const float* ae3,
                     float* sE, int FE, float invE) {
    __shared__ float red[256];
    __shared__ float uu[64];
    int t = threadIdx.x;
    if (t < 3 * FE) {
        int l = t / FE, f = t % FE;
        const float* We = (l == 0) ? We1 : (l == 1) ? We2 : We3;
        const float* ae = (l == 0) ? ae1 : (l == 1) ? ae2 : ae3;
        float s = 0.f;
        for (int hh = 0; hh < HD; ++hh) s += We[f * HD + hh] * ae[hh];
        uu[t] = s;
    }
    int col = t & 15, grp = t >> 4;
    float s = 0.f;
    for (int b = grp; b < NB; b += 16) s += partials[b * FE + col];
    red[t] = s;
    __syncthreads();
    if (t < 16) {
        float v = 0.f;
        for (int g = 0; g < 16; ++g) v += red[g * 16 + t];
        red[t] = v * invE;  // mean_ea[col]
    }
    __syncthreads();
    if (t < 3) {
        float a = 0.f;
        for (int f = 0; f < FE; ++f) a += red[f] * uu[t * FE + f];
        sE[t] = a;  // self-loop alpha_e for layer t
    }
}

// ---------------- 3-stage parallel exclusive scan over (cnt + 1 self-loop) ----------------
__global__ void k_scanA(const int* __restrict__ cnt, int* pre, int* blocksums, int N) {
    __shared__ int lds[256];
    int t = threadIdx.x;
    int n = blockIdx.x * 256 + t;
    int v = (n < N) ? cnt[n] + 1 : 0;
    lds[t] = v;
    __syncthreads();
    for (int d = 1; d < 256; d <<= 1) {
        int x = (t >= d) ? lds[t - d] : 0;
        __syncthreads();
        lds[t] += x;
        __syncthreads();
    }
    if (n < N) pre[n] = lds[t] - v;
    if (t == 255) blocksums[blockIdx.x] = lds[255];
}

__global__ void k_scanB(int* blocksums, int NBLK, int* total) {
    __shared__ int lds[256];
    int t = threadIdx.x;
    int v = (t < NBLK) ? blocksums[t] : 0;
    lds[t] = v;
    __syncthreads();
    for (int d = 1; d < 256; d <<= 1) {
        int x = (t >= d) ? lds[t - d] : 0;
        __syncthreads();
        lds[t] += x;
        __syncthreads();
    }
    if (t < NBLK) blocksums[t] = lds[t] - v;
    if (t == 255) *total = lds[255];
}

// C: combine -> row_ptr, fill = row_ptr+1, AND write self-loop record
__global__ void k_scanC(const int* __restrict__ pre, const int* __restrict__ blocksums,
                        const int* __restrict__ total, int* row_ptr, int* fill,
                        u64* __restrict__ rec, const float* __restrict__ sE, int N) {
    int n = blockIdx.x * 256 + threadIdx.x;
    if (n < N) {
        int r = pre[n] + blocksums[blockIdx.x];
        row_ptr[n] = r;
        fill[n] = r + 1;
        rec[r] = pack_rec(n, sE[0], sE[1], sE[2]);
    }
    if (n == 0) row_ptr[N] = *total;
}

// ---------------- permutation scatter: recE (edge order) -> rec (CSR order) ----------------
__global__ void k_perm(const int* __restrict__ ei, const u64* __restrict__ recE,
                       int E, int* fill, u64* __restrict__ rec) {
    int e = blockIdx.x * 256 + threadIdx.x;
    if (e < E) {
        u64 r = recE[e];
        int dst = ei[E + e];
        int pos = atomicAdd(&fill[dst], 1);
        rec[pos] = r;
    }
}

// ---------------- MFMA GEMM: h(f16) = x @ W ; as_n = h.a_s ; ad_n = h.a_d ----------------
// block = 256 threads (4 waves), 64 nodes/block, 64 cols, K in {128,64}
// xin is fp32 (in_f16=0) or f16 (in_f16=1)
__global__ void k_gemm(const void* __restrict__ xin, int in_f16,
                       const float* __restrict__ W,
                       const float* __restrict__ a_s, const float* __restrict__ a_d,
                       __half* __restrict__ h, float* __restrict__ as_n,
                       float* __restrict__ ad_n, int N, int K) {
    extern __shared__ char smem[];
    const int SK = K + 8;
    f16* xs = (f16*)smem;          // 64*SK
    f16* wt = xs + 64 * SK;        // 64*SK
    int t = threadIdx.x;
    int nb = blockIdx.x * 64;

    int nK4 = K >> 2;
    if (in_f16) {
        const __half* xh = (const __half*)xin;
        for (int i = t; i < 64 * nK4; i += 256) {
            int row = i / nK4, c4 = i % nK4;
            int gr = nb + row; if (gr >= N) gr = N - 1;
            u64 v = ((const u64*)(xh + (size_t)gr * K))[c4];  // 4 halves
            *(u64*)&xs[row * SK + c4 * 4] = v;
        }
    } else {
        const float* xf = (const float*)xin;
        for (int i = t; i < 64 * nK4; i += 256) {
            int row = i / nK4, c4 = i % nK4;
            int gr = nb + row; if (gr >= N) gr = N - 1;
            float4 v = ((const float4*)(xf + (size_t)gr * K))[c4];
            f16* p = &xs[row * SK + c4 * 4];
            p[0] = (f16)v.x; p[1] = (f16)v.y; p[2] = (f16)v.z; p[3] = (f16)v.w;
        }
    }
    // stage W transposed (coalesced global read)
    for (int i = t; i < K * 64; i += 256) {
        int k = i >> 6, c = i & 63;
        wt[c * SK + k] = (f16)W[i];
    }
    __syncthreads();

    int wv = t >> 6, lane = t & 63;
    int m = lane & 15, quad = lane >> 4;
    int rowA = wv * 16 + m;

    f32x4 acc[4];
#pragma unroll
    for (int ct = 0; ct < 4; ++ct) acc[ct] = (f32x4){0.f, 0.f, 0.f, 0.f};

    for (int ks = 0; ks < (K >> 5); ++ks) {
        f16x8 a = *(const f16x8*)&xs[rowA * SK + ks * 32 + quad * 8];
#pragma unroll
        for (int ct = 0; ct < 4; ++ct) {
            f16x8 bf = *(const f16x8*)&wt[(ct * 16 + m) * SK + ks * 32 + quad * 8];
            acc[ct] = __builtin_amdgcn_mfma_f32_16x16x32_f16(a, bf, acc[ct], 0, 0, 0);
        }
    }

    __syncthreads();  // done reading xs/wt; reuse xs as ht
    f16* ht = xs;
    const int HS = 72;
#pragma unroll
    for (int ct = 0; ct < 4; ++ct)
#pragma unroll
        for (int r = 0; r < 4; ++r) {
            int rl = wv * 16 + quad * 4 + r;
            ht[rl * HS + ct * 16 + m] = (f16)acc[ct][r];
        }
    __syncthreads();

    // coalesced global write of h (f16): 4 threads/row, 16 halves each (2 x 16B)
    {
        int row = t >> 2, cb = (t & 3) * 16;
        int gr = nb + row;
        if (gr < N) {
            ulonglong2 v0 = *(const ulonglong2*)&ht[row * HS + cb];
            ulonglong2 v1 = *(const ulonglong2*)&ht[row * HS + cb + 8];
            *(ulonglong2*)(h + (size_t)gr * HD + cb) = v0;
            *(ulonglong2*)(h + (size_t)gr * HD + cb + 8) = v1;
        }
    }
    // per-node dots with a_s, a_d (wave handles 16 rows)
    float ac = a_s[lane], adc = a_d[lane];
    for (int rr = 0; rr < 16; ++rr) {
        int row = wv * 16 + rr, gr = nb + row;
        float v = (float)ht[row * HS + lane];
        float vs = v * ac, vd = v * adc;
#pragma unroll
        for (int dd = 32; dd; dd >>= 1) {
            vs += __shfl_down(vs, dd, 64);
            vd += __shfl_down(vd, dd, 64);
        }
        if (lane == 0 && gr < N) { as_n[gr] = vs; ad_n[gr] = vd; }
    }
}

// ---------------- per-node aggregation: lane-parallel alpha + shuffle-broadcast FMA ----------------
__global__ void k_aggr(const __half* __restrict__ h, const float* __restrict__ as_n,
                       const float* __restrict__ ad_n, const int* __restrict__ row_ptr,
                       const u64* __restrict__ rec, int l,
                       const float* __restrict__ b, __half* __restrict__ x_out,
                       float* __restrict__ emb, int N, int first) {
    int wave = threadIdx.x >> 6, lane = threadIdx.x & 63;
    int n = blockIdx.x * 4 + wave;
    if (n >= N) return;
    int base = row_ptr[n], end = row_ptr[n + 1];
    float adv = ad_n[n];
    const int shift = 16 * (l + 1);
    float m = -INFINITY, d = 0.f, acc = 0.f;

    for (int c = base; c < end; c += 64) {
        int cnt = min(64, end - c);
        float a = -INFINITY;
        int s = 0;
        if (lane < cnt) {
            u64 r = rec[c + lane];
            s = (int)(r & 0xFFFFull);
            float aE = __half2float(__ushort_as_half((unsigned short)(r >> shift)));
            a = as_n[s] + adv + aE;
            a = (a > 0.f) ? a : 0.2f * a;
        }
        float mc = a;
#pragma unroll
        for (int dd = 32; dd; dd >>= 1) mc = fmaxf(mc, __shfl_xor(mc, dd, 64));
        float mn = fmaxf(m, mc);
        float w = (lane < cnt) ? __expf(a - mn) : 0.f;
        float dc = w;
#pragma unroll
        for (int dd = 32; dd; dd >>= 1) dc += __shfl_xor(dc, dd, 64);
        float sc = __expf(m - mn);
        d = d * sc + dc;
        acc = acc * sc;
        m = mn;
        int j = 0;
        for (; j + 3 < cnt; j += 4) {
            int s0 = __shfl(s, j, 64), s1 = __shfl(s, j + 1, 64),
                s2 = __shfl(s, j + 2, 64), s3 = __shfl(s, j + 3, 64);
            float w0 = __shfl(w, j, 64), w1 = __shfl(w, j + 1, 64),
                  w2 = __shfl(w, j + 2, 64), w3 = __shfl(w, j + 3, 64);
            float h0 = __half2float(h[(size_t)s0 * HD + lane]);
            float h1 = __half2float(h[(size_t)s1 * HD + lane]);
            float h2 = __half2float(h[(size_t)s2 * HD + lane]);
            float h3 = __half2float(h[(size_t)s3 * HD + lane]);
            acc += w0 * h0; acc += w1 * h1; acc += w2 * h2; acc += w3 * h3;
        }
        for (; j < cnt; ++j) {
            int sj = __shfl(s, j, 64);
            float wj = __shfl(w, j, 64);
            acc += wj * __half2float(h[(size_t)sj * HD + lane]);
        }
    }

    float out = acc / (d + 1e-16f) + b[lane];
    float v = (out > 0.f) ? out : expm1f(out);
    x_out[(size_t)n * HD + lane] = __float2half(v);
    if (first) emb[(size_t)n * HD + lane] = v;
    else emb[(size_t)n * HD + lane] += v;
}

// ---------------- column sums of emb -> gacc (atomic) ----------------
__global__ void k_red(const float* __restrict__ emb, float* gacc, int N) {
    __shared__ float lds[256];
    int f = threadIdx.x & 63, w = threadIdx.x >> 6;
    float s = 0.f;
    for (int n = blockIdx.x * 4 + w; n < N; n += gridDim.x * 4)
        s += emb[(size_t)n * HD + f];
    lds[threadIdx.x] = s;
    __syncthreads();
    if (w == 0) {
        float v = lds[f] + lds[64 + f] + lds[128 + f] + lds[192 + f];
        atomicAdd(&gacc[f], v);
    }
}

__global__ void k_div(const float* __restrict__ gacc, float* out, int N) {
    int f = threadIdx.x;
    if (f < HD) out[(size_t)N * HD + f] = gacc[f] / (float)N;
}

extern "C" void kernel_launch(void* const* d_in, const int* in_sizes, int n_in,
                              void* d_out, int out_size, void* d_ws, size_t ws_size,
                              hipStream_t stream) {
    const float* x = (const float*)d_in[0];
    const int* ei = (const int*)d_in[1];
    const float* ea = (const float*)d_in[2];

    const int FIN = in_sizes[3] / HD;       // W1 is [F_IN, 64]
    const int N = in_sizes[0] / FIN;
    const int E = in_sizes[1] / 2;
    const int FE = in_sizes[2] / E;
    const int Ep = E + N;

    const float* W[3];  const float* as_[3]; const float* ad_[3];
    const float* We[3]; const float* ae_[3]; const float* bb[3];
    for (int l = 0; l < 3; ++l) {
        W[l]  = (const float*)d_in[3 + 6 * l + 0];
        as_[l] = (const float*)d_in[3 + 6 * l + 1];
        ad_[l] = (const float*)d_in[3 + 6 * l + 2];
        We[l] = (const float*)d_in[3 + 6 * l + 3];
        ae_[l] = (const float*)d_in[3 + 6 * l + 4];
        bb[l] = (const float*)d_in[3 + 6 * l + 5];
    }

    int gN = (N + 255) / 256;
    int gE = (E + 255) / 256;

    // ---- workspace layout (bytes, 256-aligned) ----
    char* ws = (char*)d_ws;
    size_t off = 0;
    auto alloc = [&](size_t bytes) {
        void* p = ws + off;
        off += (bytes + 255) & ~(size_t)255;
        return p;
    };
    __half* h      = (__half*)alloc((size_t)N * HD * 2);
    __half* x_cur  = (__half*)alloc((size_t)N * HD * 2);
    float*  as_n   = (float*)alloc((size_t)N * 4);
    float*  ad_n   = (float*)alloc((size_t)N * 4);
    int*    cnt    = (int*)alloc((size_t)N * 4);
    int*    rowp   = (int*)alloc((size_t)(N + 1) * 4);
    int*    fill   = (int*)alloc((size_t)N * 4);
    int*    pre    = (int*)alloc((size_t)N * 4);
    int*    bsums  = (int*)alloc(256 * 4);
    int*    total  = (int*)alloc(4);
    u64*    rec    = (u64*)alloc((size_t)Ep * 8);
    u64*    recE   = (u64*)alloc((size_t)E * 8);
    float*  partials = (float*)alloc((size_t)gE * FE * 4);
    float*  sE     = (float*)alloc(3 * 4);
    float*  gacc   = (float*)alloc(HD * 4);
    (void)ws_size; (void)n_in; (void)out_size;

    float* emb = (float*)d_out;

    k_init<<<gN, 256, 0, stream>>>(cnt, gacc, N);
    size_t pre_lds = (size_t)(256 * (FE + 1) + 3 * FE + 256 * 4) * 4;
    k_pre<<<gE, 256, pre_lds, stream>>>(ei, ea, We[0], ae_[0], We[1], ae_[1],
                                        We[2], ae_[2], E, FE, cnt, recE, partials);
    k_u2<<<1, 256, 0, stream>>>(partials, gE, We[0], ae_[0], We[1], ae_[1],
                                We[2], ae_[2], sE, FE, 1.0f / (float)E);
    k_scanA<<<gN, 256, 0, stream>>>(cnt, pre, bsums, N);
    k_scanB<<<1, 256, 0, stream>>>(bsums, gN, total);
    k_scanC<<<gN, 256, 0, stream>>>(pre, bsums, total, rowp, fill, rec, sE, N);
    k_perm<<<gE, 256, 0, stream>>>(ei, recE, E, fill, rec);

    for (int l = 0; l < 3; ++l) {
        const void* xin = (l == 0) ? (const void*)x : (const void*)x_cur;
        int in_f16 = (l == 0) ? 0 : 1;
        int K = (l == 0) ? FIN : HD;
        size_t ldsz = (size_t)(2 * 64 * (K + 8)) * 2;  // xs + wt, f16
        k_gemm<<<(N + 63) / 64, 256, ldsz, stream>>>(xin, in_f16, W[l], as_[l], ad_[l],
                                                     h, as_n, ad_n, N, K);
        k_aggr<<<(N + 3) / 4, 256, 0, stream>>>(h, as_n, ad_n, rowp, rec, l,
                                                bb[l], x_cur, emb, N, (l == 0) ? 1 : 0);
    }

    k_red<<<256, 256, 0, stream>>>(emb, gacc, N);
    k_div<<<1, 64, 0, stream>>>(gacc, emb, N);
}

// Round 10
// 424.555 us; speedup vs baseline: 1.1114x; 1.1114x over previous
//
#include <hip/hip_runtime.h>
#include <hip/hip_fp16.h>
#include <math.h>

#define HD 64       // hidden dim H
#define MAXNBK 256  // max dst-range buckets (256 nodes per bucket)

typedef unsigned long long u64;
typedef _Float16 f16;
typedef _Float16 f16x8 __attribute__((ext_vector_type(8)));
typedef float f32x4 __attribute__((ext_vector_type(4)));

__device__ __forceinline__ u64 pack_rec(int src, float a0, float a1, float a2) {
    return (u64)(src & 0xFFFF)
         | ((u64)__half_as_ushort(__float2half(a0)) << 16)
         | ((u64)__half_as_ushort(__float2half(a1)) << 32)
         | ((u64)__half_as_ushort(__float2half(a2)) << 48);
}

// ---------------- init: zero cnt, bucket counters (padded), gacc ----------------
__global__ void k_init(int* cnt, int* bcnt, float* gacc, int N, int NBK) {
    int i = blockIdx.x * blockDim.x + threadIdx.x;
    if (i < N) cnt[i] = 0;
    if (i < NBK * 16) bcnt[i] = 0;
    if (i < HD) gacc[i] = 0.f;
}

// ---------------- grid-stride ea pass: alphas -> recE (edge order, coalesced),
// colsum partials, per-node hist, per-bucket hist (LDS-aggregated) ----------------
__global__ void k_pre(const int* __restrict__ ei, const float* __restrict__ ea,
                      const float* We1, const float* ae1,
                      const float* We2, const float* ae2,
                      const float* We3, const float* ae3,
                      int E, int FE, int ntiles, int NBK,
                      int* cnt, int* bcnt, u64* __restrict__ recE,
                      float* __restrict__ partials) {
    extern __shared__ float lds[];
    float* sEA = lds;                           // 256*(FE+1)
    float* su = sEA + 256 * (FE + 1);           // 3*FE
    float* colacc = su + 3 * FE;                // 256*4
    int* lcnt = (int*)(colacc + 256 * 4);       // MAXNBK
    int t = threadIdx.x;
    int ldE = FE + 1;

    if (t < 3 * FE) {
        int l = t / FE, f = t % FE;
        const float* We = (l == 0) ? We1 : (l == 1) ? We2 : We3;
        const float* ae = (l == 0) ? ae1 : (l == 1) ? ae2 : ae3;
        float s = 0.f;
        for (int hh = 0; hh < HD; ++hh) s += We[f * HD + hh] * ae[hh];
        su[t] = s;
    }
    lcnt[t] = 0;

    const float4* ea4 = (const float4*)ea;
    size_t tot4 = (size_t)E * FE / 4;
    int per_tile4 = 64 * FE;  // float4s per 256-edge tile
    float4 acc = make_float4(0.f, 0.f, 0.f, 0.f);

    for (int tile = blockIdx.x; tile < ntiles; tile += gridDim.x) {
        __syncthreads();  // protect sEA reuse; makes su/lcnt visible on first iter
        size_t base4 = (size_t)tile * per_tile4;
        for (int i = t; i < per_tile4; i += 256) {
            size_t g4 = base4 + i;
            if (g4 < tot4) {
                float4 v = ea4[g4];
                acc.x += v.x; acc.y += v.y; acc.z += v.z; acc.w += v.w;
                int g = i * 4;
                int e_loc = g / FE, f = g % FE;
                float* p = &sEA[e_loc * ldE + f];
                p[0] = v.x; p[1] = v.y; p[2] = v.z; p[3] = v.w;
            }
        }
        __syncthreads();
        int e = tile * 256 + t;
        if (e < E) {
            float a0 = 0.f, a1 = 0.f, a2 = 0.f;
            const float* row = &sEA[t * ldE];
            for (int f = 0; f < FE; ++f) {
                float v = row[f];
                a0 += v * su[f];
                a1 += v * su[FE + f];
                a2 += v * su[2 * FE + f];
            }
            int src = ei[e], dst = ei[E + e];
            recE[e] = pack_rec(src, a0, a1, a2);
            atomicAdd(&cnt[dst], 1);
            atomicAdd(&lcnt[dst >> 8], 1);
        }
    }

    colacc[t * 4 + 0] = acc.x; colacc[t * 4 + 1] = acc.y;
    colacc[t * 4 + 2] = acc.z; colacc[t * 4 + 3] = acc.w;
    __syncthreads();
    if (t < NBK && lcnt[t]) atomicAdd(&bcnt[t * 16], lcnt[t]);
    if (t < 16) {
        int q = t >> 2, j = t & 3;  // feature = q*4 + j (thread with t%4==q holds quartet q)
        float s = 0.f;
        for (int k = 0; k < 64; ++k) s += colacc[(q + k * 4) * 4 + j];
        partials[blockIdx.x * 16 + (q * 4 + j)] = s;
    }
}

// ---------------- partials -> sE ; bucket scan -> bbase + bfill init ----------------
__global__ void k_u2(const float* __restrict__ partials, int NB,
                     const float* We1, const float* ae1,
                     const float* We2, const float* ae2,
                     const float* We3, const float* ae3,
                     float* sE, int FE, float invE,
                     int* bcnt /* padded; becomes bfill */, int* bbase, int NBK, int E) {
    __shared__ float red[256];
    __shared__ float uu[64];
    __shared__ int bs[256];
    int t = threadIdx.x;
    if (t < 3 * FE) {
        int l = t / FE, f = t % FE;
        const float* We = (l == 0) ? We1 : (l == 1) ? We2 : We3;
        const float* ae = (l == 0) ? ae1 : (l == 1) ? ae2 : ae3;
        float s = 0.f;
        for (int hh = 0; hh < HD; ++hh) s += We[f * HD + hh] * ae[hh];
        uu[t] = s;
    }
    int col = t & 15, grp = t >> 4;
    float s = 0.f;
    for (int b = grp; b < NB; b += 16) s += partials[b * FE + col];
    red[t] = s;
    int v = (t < NBK) ? bcnt[t * 16] : 0;
    bs[t] = v;
    __syncthreads();
    for (int d = 1; d < 256; d <<= 1) {
        int x = (t >= d) ? bs[t - d] : 0;
        __syncthreads();
        bs[t] += x;
        __syncthreads();
    }
    int pre = bs[t] - v;  // exclusive
    if (t < NBK) { bbase[t] = pre; bcnt[t * 16] = pre; }
    if (t == 0) bbase[NBK] = E;
    if (t < 16) {
        float v2 = 0.f;
        for (int g = 0; g < 16; ++g) v2 += red[g * 16 + t];
        red[t] = v2 * invE;  // mean_ea[col]
    }
    __syncthreads();
    if (t < 3) {
        float a = 0.f;
        for (int f = 0; f < FE; ++f) a += red[f] * uu[t * FE + f];
        sE[t] = a;
    }
}

// ---------------- 3-stage parallel exclusive scan over (cnt + 1 self-loop) ----------------
__global__ void k_scanA(const int* __restrict__ cnt, int* pre, int* blocksums, int N) {
    __shared__ int lds[256];
    int t = threadIdx.x;
    int n = blockIdx.x * 256 + t;
    int v = (n < N) ? cnt[n] + 1 : 0;
    lds[t] = v;
    __syncthreads();
    for (int d = 1; d < 256; d <<= 1) {
        int x = (t >= d) ? lds[t - d] : 0;
        __syncthreads();
        lds[t] += x;
        __syncthreads();
    }
    if (n < N) pre[n] = lds[t] - v;
    if (t == 255) blocksums[blockIdx.x] = lds[255];
}

__global__ void k_scanB(int* blocksums, int NBLK, int* total) {
    __shared__ int lds[256];
    int t = threadIdx.x;
    int v = (t < NBLK) ? blocksums[t] : 0;
    lds[t] = v;
    __syncthreads();
    for (int d = 1; d < 256; d <<= 1) {
        int x = (t >= d) ? lds[t - d] : 0;
        __syncthreads();
        lds[t] += x;
        __syncthreads();
    }
    if (t < NBLK) blocksums[t] = lds[t] - v;
    if (t == 255) *total = lds[255];
}

// C: combine -> row_ptr; write self-loop record at slot 0 of each segment
__global__ void k_scanC(const int* __restrict__ pre, const int* __restrict__ blocksums,
                        const int* __restrict__ total, int* row_ptr,
                        u64* __restrict__ rec, const float* __restrict__ sE, int N) {
    int n = blockIdx.x * 256 + threadIdx.x;
    if (n < N) {
        int r = pre[n] + blocksums[blockIdx.x];
        row_ptr[n] = r;
        rec[r] = pack_rec(n, sE[0], sE[1], sE[2]);
    }
    if (n == 0) row_ptr[N] = *total;
}

// ---------------- pass 2: bin records by dst bucket (sequential-per-bucket writes) ----------------
__global__ void k_bucket(const int* __restrict__ ei, const u64* __restrict__ recE,
                         int E, int chunk, int* bfill /* padded */,
                         u64* __restrict__ binned, unsigned char* __restrict__ bdstl,
                         int NBK) {
    __shared__ int lcnt[MAXNBK], gb[MAXNBK], lrank[MAXNBK];
    int t = threadIdx.x;
    lcnt[t] = 0;
    __syncthreads();
    int lo = blockIdx.x * chunk, hi = min(E, lo + chunk);
    for (int e = lo + t; e < hi; e += 256)
        atomicAdd(&lcnt[ei[E + e] >> 8], 1);
    __syncthreads();
    if (t < NBK) {
        lrank[t] = 0;
        gb[t] = lcnt[t] ? atomicAdd(&bfill[t * 16], lcnt[t]) : 0;
    }
    __syncthreads();
    for (int e = lo + t; e < hi; e += 256) {
        u64 r = recE[e];
        int dst = ei[E + e];
        int b = dst >> 8;
        int rank = atomicAdd(&lrank[b], 1);
        int pos = gb[b] + rank;
        binned[pos] = r;
        bdstl[pos] = (unsigned char)(dst & 255);
    }
}

// ---------------- pass 3: per-bucket distribute to final CSR slots ----------------
__global__ void k_sort(const int* __restrict__ bbase, const int* __restrict__ row_ptr,
                       const u64* __restrict__ binned, const unsigned char* __restrict__ bdstl,
                       u64* __restrict__ rec, int N) {
    __shared__ int lfill[256];
    int b = blockIdx.x, t = threadIdx.x;
    int gnode = (b << 8) + t;
    lfill[t] = (gnode < N) ? row_ptr[gnode] + 1 : 0;  // +1: self-loop at slot 0
    __syncthreads();
    int base = bbase[b], nrec = bbase[b + 1] - base;
    for (int i = t; i < nrec; i += 256) {
        u64 r = binned[base + i];
        int dl = bdstl[base + i];
        int p = atomicAdd(&lfill[dl], 1);
        rec[p] = r;
    }
}

// ---------------- MFMA GEMM: h(f16) = x @ W ; as_n = h.a_s ; ad_n = h.a_d ----------------
__global__ void k_gemm(const void* __restrict__ xin, int in_f16,
                       const float* __restrict__ W,
                       const float* __restrict__ a_s, const float* __restrict__ a_d,
                       __half* __restrict__ h, float* __restrict__ as_n,
                       float* __restrict__ ad_n, int N, int K) {
    extern __shared__ char smem[];
    const int SK = K + 8;
    f16* xs = (f16*)smem;          // 64*SK
    f16* wt = xs + 64 * SK;        // 64*SK
    int t = threadIdx.x;
    int nb = blockIdx.x * 64;

    int nK4 = K >> 2;
    if (in_f16) {
        const __half* xh = (const __half*)xin;
        for (int i = t; i < 64 * nK4; i += 256) {
            int row = i / nK4, c4 = i % nK4;
            int gr = nb + row; if (gr >= N) gr = N - 1;
            u64 v = ((const u64*)(xh + (size_t)gr * K))[c4];
            *(u64*)&xs[row * SK + c4 * 4] = v;
        }
    } else {
        const float* xf = (const float*)xin;
        for (int i = t; i < 64 * nK4; i += 256) {
            int row = i / nK4, c4 = i % nK4;
            int gr = nb + row; if (gr >= N) gr = N - 1;
            float4 v = ((const float4*)(xf + (size_t)gr * K))[c4];
            f16* p = &xs[row * SK + c4 * 4];
            p[0] = (f16)v.x; p[1] = (f16)v.y; p[2] = (f16)v.z; p[3] = (f16)v.w;
        }
    }
    for (int i = t; i < K * 64; i += 256) {
        int k = i >> 6, c = i & 63;
        wt[c * SK + k] = (f16)W[i];
    }
    __syncthreads();

    int wv = t >> 6, lane = t & 63;
    int m = lane & 15, quad = lane >> 4;
    int rowA = wv * 16 + m;

    f32x4 acc[4];
#pragma unroll
    for (int ct = 0; ct < 4; ++ct) acc[ct] = (f32x4){0.f, 0.f, 0.f, 0.f};

    for (int ks = 0; ks < (K >> 5); ++ks) {
        f16x8 a = *(const f16x8*)&xs[rowA * SK + ks * 32 + quad * 8];
#pragma unroll
        for (int ct = 0; ct < 4; ++ct) {
            f16x8 bf = *(const f16x8*)&wt[(ct * 16 + m) * SK + ks * 32 + quad * 8];
            acc[ct] = __builtin_amdgcn_mfma_f32_16x16x32_f16(a, bf, acc[ct], 0, 0, 0);
        }
    }

    __syncthreads();
    f16* ht = xs;
    const int HS = 72;
#pragma unroll
    for (int ct = 0; ct < 4; ++ct)
#pragma unroll
        for (int r = 0; r < 4; ++r) {
            int rl = wv * 16 + quad * 4 + r;
            ht[rl * HS + ct * 16 + m] = (f16)acc[ct][r];
        }
    __syncthreads();

    {
        int row = t >> 2, cb = (t & 3) * 16;
        int gr = nb + row;
        if (gr < N) {
            ulonglong2 v0 = *(const ulonglong2*)&ht[row * HS + cb];
            ulonglong2 v1 = *(const ulonglong2*)&ht[row * HS + cb + 8];
            *(ulonglong2*)(h + (size_t)gr * HD + cb) = v0;
            *(ulonglong2*)(h + (size_t)gr * HD + cb + 8) = v1;
        }
    }
    float ac = a_s[lane], adc = a_d[lane];
    for (int rr = 0; rr < 16; ++rr) {
        int row = wv * 16 + rr, gr = nb + row;
        float v = (float)ht[row * HS + lane];
        float vs = v * ac, vd = v * adc;
#pragma unroll
        for (int dd = 32; dd; dd >>= 1) {
            vs += __shfl_down(vs, dd, 64);
            vd += __shfl_down(vd, dd, 64);
        }
        if (lane == 0 && gr < N) { as_n[gr] = vs; ad_n[gr] = vd; }
    }
}

// ---------------- per-node aggregation: lane-parallel alpha + shuffle-broadcast FMA ----------------
__global__ void k_aggr(const __half* __restrict__ h, const float* __restrict__ as_n,
                       const float* __restrict__ ad_n, const int* __restrict__ row_ptr,
                       const u64* __restrict__ rec, int l,
                       const float* __restrict__ b, __half* __restrict__ x_out,
                       float* __restrict__ emb, int N, int first) {
    int wave = threadIdx.x >> 6, lane = threadIdx.x & 63;
    int n = blockIdx.x * 4 + wave;
    if (n >= N) return;
    int base = row_ptr[n], end = row_ptr[n + 1];
    float adv = ad_n[n];
    const int shift = 16 * (l + 1);
    float m = -INFINITY, d = 0.f, acc = 0.f;

    for (int c = base; c < end; c += 64) {
        int cnt = min(64, end - c);
        float a = -INFINITY;
        int s = 0;
        if (lane < cnt) {
            u64 r = rec[c + lane];
            s = (int)(r & 0xFFFFull);
            float aE = __half2float(__ushort_as_half((unsigned short)(r >> shift)));
            a = as_n[s] + adv + aE;
            a = (a > 0.f) ? a : 0.2f * a;
        }
        float mc = a;
#pragma unroll
        for (int dd = 32; dd; dd >>= 1) mc = fmaxf(mc, __shfl_xor(mc, dd, 64));
        float mn = fmaxf(m, mc);
        float w = (lane < cnt) ? __expf(a - mn) : 0.f;
        float dc = w;
#pragma unroll
        for (int dd = 32; dd; dd >>= 1) dc += __shfl_xor(dc, dd, 64);
        float sc = __expf(m - mn);
        d = d * sc + dc;
        acc = acc * sc;
        m = mn;
        int j = 0;
        for (; j + 3 < cnt; j += 4) {
            int s0 = __shfl(s, j, 64), s1 = __shfl(s, j + 1, 64),
                s2 = __shfl(s, j + 2, 64), s3 = __shfl(s, j + 3, 64);
            float w0 = __shfl(w, j, 64), w1 = __shfl(w, j + 1, 64),
                  w2 = __shfl(w, j + 2, 64), w3 = __shfl(w, j + 3, 64);
            float h0 = __half2float(h[(size_t)s0 * HD + lane]);
            float h1 = __half2float(h[(size_t)s1 * HD + lane]);
            float h2 = __half2float(h[(size_t)s2 * HD + lane]);
            float h3 = __half2float(h[(size_t)s3 * HD + lane]);
            acc += w0 * h0; acc += w1 * h1; acc += w2 * h2; acc += w3 * h3;
        }
        for (; j < cnt; ++j) {
            int sj = __shfl(s, j, 64);
            float wj = __shfl(w, j, 64);
            acc += wj * __half2float(h[(size_t)sj * HD + lane]);
        }
    }

    float out = acc / (d + 1e-16f) + b[lane];
    float v = (out > 0.f) ? out : expm1f(out);
    x_out[(size_t)n * HD + lane] = __float2half(v);
    if (first) emb[(size_t)n * HD + lane] = v;
    else emb[(size_t)n * HD + lane] += v;
}

// ---------------- column sums of emb -> gacc (atomic) ----------------
__global__ void k_red(const float* __restrict__ emb, float* gacc, int N) {
    __shared__ float lds[256];
    int f = threadIdx.x & 63, w = threadIdx.x >> 6;
    float s = 0.f;
    for (int n = blockIdx.x * 4 + w; n < N; n += gridDim.x * 4)
        s += emb[(size_t)n * HD + f];
    lds[threadIdx.x] = s;
    __syncthreads();
    if (w == 0) {
        float v = lds[f] + lds[64 + f] + lds[128 + f] + lds[192 + f];
        atomicAdd(&gacc[f], v);
    }
}

__global__ void k_div(const float* __restrict__ gacc, float* out, int N) {
    int f = threadIdx.x;
    if (f < HD) out[(size_t)N * HD + f] = gacc[f] / (float)N;
}

extern "C" void kernel_launch(void* const* d_in, const int* in_sizes, int n_in,
                              void* d_out, int out_size, void* d_ws, size_t ws_size,
                              hipStream_t stream) {
    const float* x = (const float*)d_in[0];
    const int* ei = (const int*)d_in[1];
    const float* ea = (const float*)d_in[2];

    const int FIN = in_sizes[3] / HD;       // W1 is [F_IN, 64]
    const int N = in_sizes[0] / FIN;
    const int E = in_sizes[1] / 2;
    const int FE = in_sizes[2] / E;
    const int Ep = E + N;
    const int NBK = (N + 255) >> 8;         // dst buckets of 256 nodes
    const int NPRE = 512;                   // k_pre / k_bucket blocks

    const float* W[3];  const float* as_[3]; const float* ad_[3];
    const float* We[3]; const float* ae_[3]; const float* bb[3];
    for (int l = 0; l < 3; ++l) {
        W[l]  = (const float*)d_in[3 + 6 * l + 0];
        as_[l] = (const float*)d_in[3 + 6 * l + 1];
        ad_[l] = (const float*)d_in[3 + 6 * l + 2];
        We[l] = (const float*)d_in[3 + 6 * l + 3];
        ae_[l] = (const float*)d_in[3 + 6 * l + 4];
        bb[l] = (const float*)d_in[3 + 6 * l + 5];
    }

    int gN = (N + 255) / 256;
    int ntiles = (E + 255) / 256;
    int chunk = (E + NPRE - 1) / NPRE;

    // ---- workspace layout (bytes, 256-aligned) ----
    char* ws = (char*)d_ws;
    size_t off = 0;
    auto alloc = [&](size_t bytes) {
        void* p = ws + off;
        off += (bytes + 255) & ~(size_t)255;
        return p;
    };
    __half* h      = (__half*)alloc((size_t)N * HD * 2);
    __half* x_cur  = (__half*)alloc((size_t)N * HD * 2);
    float*  as_n   = (float*)alloc((size_t)N * 4);
    float*  ad_n   = (float*)alloc((size_t)N * 4);
    int*    cnt    = (int*)alloc((size_t)N * 4);
    int*    rowp   = (int*)alloc((size_t)(N + 1) * 4);
    int*    pre    = (int*)alloc((size_t)N * 4);
    int*    bsums  = (int*)alloc(256 * 4);
    int*    total  = (int*)alloc(4);
    int*    bcnt   = (int*)alloc((size_t)MAXNBK * 16 * 4);  // padded (64B/bucket); becomes bfill
    int*    bbase  = (int*)alloc((size_t)(MAXNBK + 1) * 4);
    u64*    rec    = (u64*)alloc((size_t)Ep * 8);
    u64*    recE   = (u64*)alloc((size_t)E * 8);
    u64*    binned = (u64*)alloc((size_t)E * 8);
    unsigned char* bdstl = (unsigned char*)alloc((size_t)E);
    float*  partials = (float*)alloc((size_t)NPRE * FE * 4);
    float*  sE     = (float*)alloc(3 * 4);
    float*  gacc   = (float*)alloc(HD * 4);
    (void)ws_size; (void)n_in; (void)out_size;

    float* emb = (float*)d_out;

    k_init<<<gN, 256, 0, stream>>>(cnt, bcnt, gacc, N, NBK);
    size_t pre_lds = (size_t)(256 * (FE + 1) + 3 * FE + 256 * 4) * 4 + MAXNBK * 4;
    k_pre<<<NPRE, 256, pre_lds, stream>>>(ei, ea, We[0], ae_[0], We[1], ae_[1],
                                          We[2], ae_[2], E, FE, ntiles, NBK,
                                          cnt, bcnt, recE, partials);
    k_u2<<<1, 256, 0, stream>>>(partials, NPRE, We[0], ae_[0], We[1], ae_[1],
                                We[2], ae_[2], sE, FE, 1.0f / (float)E,
                                bcnt, bbase, NBK, E);
    k_scanA<<<gN, 256, 0, stream>>>(cnt, pre, bsums, N);
    k_scanB<<<1, 256, 0, stream>>>(bsums, gN, total);
    k_scanC<<<gN, 256, 0, stream>>>(pre, bsums, total, rowp, rec, sE, N);
    k_bucket<<<NPRE, 256, 0, stream>>>(ei, recE, E, chunk, bcnt, binned, bdstl, NBK);
    k_sort<<<NBK, 256, 0, stream>>>(bbase, rowp, binned, bdstl, rec, N);

    for (int l = 0; l < 3; ++l) {
        const void* xin = (l == 0) ? (const void*)x : (const void*)x_cur;
        int in_f16 = (l == 0) ? 0 : 1;
        int K = (l == 0) ? FIN : HD;
        size_t ldsz = (size_t)(2 * 64 * (K + 8)) * 2;  // xs + wt, f16
        k_gemm<<<(N + 63) / 64, 256, ldsz, stream>>>(xin, in_f16, W[l], as_[l], ad_[l],
                                                     h, as_n, ad_n, N, K);
        k_aggr<<<(N + 3) / 4, 256, 0, stream>>>(h, as_n, ad_n, rowp, rec, l,
                                                bb[l], x_cur, emb, N, (l == 0) ? 1 : 0);
    }

    k_red<<<256, 256, 0, stream>>>(emb, gacc, N);
    k_div<<<1, 64, 0, stream>>>(gacc, emb, N);
}

// Round 11
// 413.418 us; speedup vs baseline: 1.1414x; 1.0269x over previous
//
#include <hip/hip_runtime.h>
#include <hip/hip_fp16.h>
#include <math.h>

#define HD 64       // hidden dim H
#define MAXNBK 256  // max dst-range buckets (256 nodes per bucket)

typedef unsigned long long u64;
typedef _Float16 f16;
typedef _Float16 f16x8 __attribute__((ext_vector_type(8)));
typedef float f32x4 __attribute__((ext_vector_type(4)));

__device__ __forceinline__ u64 pack_rec(int src, float a0, float a1, float a2) {
    return (u64)(src & 0xFFFF)
         | ((u64)__half_as_ushort(__float2half(a0)) << 16)
         | ((u64)__half_as_ushort(__float2half(a1)) << 32)
         | ((u64)__half_as_ushort(__float2half(a2)) << 48);
}

// ---------------- init: zero cnt, gacc ----------------
__global__ void k_init(int* cnt, float* gacc, int N) {
    int i = blockIdx.x * blockDim.x + threadIdx.x;
    if (i < N) cnt[i] = 0;
    if (i < HD) gacc[i] = 0.f;
}

// ---------------- one 256-edge tile per block: alphas -> recE, colsum partials, node hist ----------------
__global__ void k_pre(const int* __restrict__ ei, const float* __restrict__ ea,
                      const float* We1, const float* ae1,
                      const float* We2, const float* ae2,
                      const float* We3, const float* ae3,
                      int E, int FE, int* cnt, u64* __restrict__ recE,
                      float* __restrict__ partials) {
    extern __shared__ float lds[];
    float* sEA = lds;                           // 256*(FE+1)
    float* su = sEA + 256 * (FE + 1);           // 3*FE
    float* colacc = su + 3 * FE;                // 256*4
    int t = threadIdx.x;
    int ldE = FE + 1;

    if (t < 3 * FE) {
        int l = t / FE, f = t % FE;
        const float* We = (l == 0) ? We1 : (l == 1) ? We2 : We3;
        const float* ae = (l == 0) ? ae1 : (l == 1) ? ae2 : ae3;
        float s = 0.f;
        for (int hh = 0; hh < HD; ++hh) s += We[f * HD + hh] * ae[hh];
        su[t] = s;
    }

    const float4* ea4 = (const float4*)ea;
    size_t tot4 = (size_t)E * FE / 4;
    int per_tile4 = 64 * FE;  // float4s per tile (1024 for FE=16)
    size_t base4 = (size_t)blockIdx.x * per_tile4;
    float4 acc = make_float4(0.f, 0.f, 0.f, 0.f);
    for (int i = t; i < per_tile4; i += 256) {
        size_t g4 = base4 + i;
        if (g4 < tot4) {
            float4 v = ea4[g4];
            acc.x += v.x; acc.y += v.y; acc.z += v.z; acc.w += v.w;
            int g = i * 4;
            int e_loc = g / FE, f = g % FE;
            float* p = &sEA[e_loc * ldE + f];
            p[0] = v.x; p[1] = v.y; p[2] = v.z; p[3] = v.w;
        }
    }
    colacc[t * 4 + 0] = acc.x; colacc[t * 4 + 1] = acc.y;
    colacc[t * 4 + 2] = acc.z; colacc[t * 4 + 3] = acc.w;
    __syncthreads();

    int e = blockIdx.x * 256 + t;
    if (e < E) {
        float a0 = 0.f, a1 = 0.f, a2 = 0.f;
        const float* row = &sEA[t * ldE];
        for (int f = 0; f < FE; ++f) {
            float v = row[f];
            a0 += v * su[f];
            a1 += v * su[FE + f];
            a2 += v * su[2 * FE + f];
        }
        int src = ei[e], dst = ei[E + e];
        recE[e] = pack_rec(src, a0, a1, a2);
        atomicAdd(&cnt[dst], 1);
    }
    if (t < 16) {
        int q = t >> 2, j = t & 3;  // feature = q*4 + j (thread with t%4==q holds quartet q)
        float s = 0.f;
        for (int k = 0; k < 64; ++k) s += colacc[(q + k * 4) * 4 + j];
        partials[blockIdx.x * 16 + (q * 4 + j)] = s;
    }
}

// ---------------- 3-stage parallel exclusive scan over (cnt + 1 self-loop) ----------------
__global__ void k_scanA(const int* __restrict__ cnt, int* pre, int* blocksums, int N) {
    __shared__ int lds[256];
    int t = threadIdx.x;
    int n = blockIdx.x * 256 + t;
    int v = (n < N) ? cnt[n] + 1 : 0;
    lds[t] = v;
    __syncthreads();
    for (int d = 1; d < 256; d <<= 1) {
        int x = (t >= d) ? lds[t - d] : 0;
        __syncthreads();
        lds[t] += x;
        __syncthreads();
    }
    if (n < N) pre[n] = lds[t] - v;
    if (t == 255) blocksums[blockIdx.x] = lds[255];
}

__global__ void k_scanB(int* blocksums, int NBLK, int* total) {
    __shared__ int lds[256];
    int t = threadIdx.x;
    int v = (t < NBLK) ? blocksums[t] : 0;
    lds[t] = v;
    __syncthreads();
    for (int d = 1; d < 256; d <<= 1) {
        int x = (t >= d) ? lds[t - d] : 0;
        __syncthreads();
        lds[t] += x;
        __syncthreads();
    }
    if (t < NBLK) blocksums[t] = lds[t] - v;  // exclusive
    if (t == 255) *total = lds[255];
}

// ---------------- partials -> sE ; bucket bases from blocksums (no atomics) ----------------
__global__ void k_u2(const float* __restrict__ partials, int NB,
                     const float* We1, const float* ae1,
                     const float* We2, const float* ae2,
                     const float* We3, const float* ae3,
                     float* sE, int FE, float invE,
                     const int* __restrict__ blocksums /* exclusive */,
                     int* bfill /* padded */, int* bbase, int NBK, int N, int E) {
    __shared__ float red[256 * 4];
    __shared__ float uu[64];
    __shared__ float mea[16];
    int t = threadIdx.x;
    if (t < 3 * FE) {
        int l = t / FE, f = t % FE;
        const float* We = (l == 0) ? We1 : (l == 1) ? We2 : We3;
        const float* ae = (l == 0) ? ae1 : (l == 1) ? ae2 : ae3;
        float s = 0.f;
        for (int hh = 0; hh < HD; ++hh) s += We[f * HD + hh] * ae[hh];
        uu[t] = s;
    }
    // coalesced float4 reduce of partials (NB rows x 16 floats = NB*4 float4s)
    const float4* p4 = (const float4*)partials;
    int tot4 = NB * 4;
    float4 acc = make_float4(0.f, 0.f, 0.f, 0.f);
    for (int i = t; i < tot4; i += 256) {
        float4 v = p4[i];
        acc.x += v.x; acc.y += v.y; acc.z += v.z; acc.w += v.w;
    }
    red[t * 4 + 0] = acc.x; red[t * 4 + 1] = acc.y;
    red[t * 4 + 2] = acc.z; red[t * 4 + 3] = acc.w;
    // bucket bases: edges_before(b) = excl_blocksums[b] - nodes_before(b)
    if (t < NBK) {
        int nb_before = min(t * 256, N);
        int base = blocksums[t] - nb_before;
        bbase[t] = base;
        bfill[t * 16] = base;
    }
    if (t == 0) bbase[NBK] = E;
    __syncthreads();
    if (t < 16) {
        int q = t >> 2, j = t & 3;
        float s = 0.f;
        for (int k = 0; k < 64; ++k) s += red[(q + k * 4) * 4 + j];
        mea[q * 4 + j] = s * invE;  // mean_ea
    }
    __syncthreads();
    if (t < 3) {
        float a = 0.f;
        for (int f = 0; f < FE; ++f) a += mea[f] * uu[t * FE + f];
        sE[t] = a;
    }
}

// C: combine -> row_ptr; write self-loop record at slot 0 of each segment
__global__ void k_scanC(const int* __restrict__ pre, const int* __restrict__ blocksums,
                        const int* __restrict__ total, int* row_ptr,
                        u64* __restrict__ rec, const float* __restrict__ sE, int N) {
    int n = blockIdx.x * 256 + threadIdx.x;
    if (n < N) {
        int r = pre[n] + blocksums[blockIdx.x];
        row_ptr[n] = r;
        rec[r] = pack_rec(n, sE[0], sE[1], sE[2]);
    }
    if (n == 0) row_ptr[N] = *total;
}

// ---------------- pass 2: bin records by dst bucket (sequential-per-bucket writes) ----------------
__global__ void k_bucket(const int* __restrict__ ei, const u64* __restrict__ recE,
                         int E, int chunk, int* bfill /* padded */,
                         u64* __restrict__ binned, unsigned char* __restrict__ bdstl,
                         int NBK) {
    __shared__ int lcnt[MAXNBK], gb[MAXNBK], lrank[MAXNBK];
    int t = threadIdx.x;
    lcnt[t] = 0;
    __syncthreads();
    int lo = blockIdx.x * chunk, hi = min(E, lo + chunk);
    for (int e = lo + t; e < hi; e += 256)
        atomicAdd(&lcnt[ei[E + e] >> 8], 1);
    __syncthreads();
    if (t < NBK) {
        lrank[t] = 0;
        gb[t] = lcnt[t] ? atomicAdd(&bfill[t * 16], lcnt[t]) : 0;
    }
    __syncthreads();
    for (int e = lo + t; e < hi; e += 256) {
        u64 r = recE[e];
        int dst = ei[E + e];
        int b = dst >> 8;
        int rank = atomicAdd(&lrank[b], 1);
        int pos = gb[b] + rank;
        binned[pos] = r;
        bdstl[pos] = (unsigned char)(dst & 255);
    }
}

// ---------------- pass 3: per-bucket distribute to final CSR slots ----------------
__global__ void k_sort(const int* __restrict__ bbase, const int* __restrict__ row_ptr,
                       const u64* __restrict__ binned, const unsigned char* __restrict__ bdstl,
                       u64* __restrict__ rec, int N) {
    __shared__ int lfill[256];
    int b = blockIdx.x, t = threadIdx.x;
    int gnode = (b << 8) + t;
    lfill[t] = (gnode < N) ? row_ptr[gnode] + 1 : 0;  // +1: self-loop at slot 0
    __syncthreads();
    int base = bbase[b], nrec = bbase[b + 1] - base;
    for (int i = t; i < nrec; i += 256) {
        u64 r = binned[base + i];
        int dl = bdstl[base + i];
        int p = atomicAdd(&lfill[dl], 1);
        rec[p] = r;
    }
}

// ---------------- MFMA GEMM: h(f16) = x @ W ; as_n = h.a_s ; ad_n = h.a_d ----------------
__global__ void k_gemm(const void* __restrict__ xin, int in_f16,
                       const float* __restrict__ W,
                       const float* __restrict__ a_s, const float* __restrict__ a_d,
                       __half* __restrict__ h, float* __restrict__ as_n,
                       float* __restrict__ ad_n, int N, int K) {
    extern __shared__ char smem[];
    const int SK = K + 8;
    f16* xs = (f16*)smem;          // 64*SK
    f16* wt = xs + 64 * SK;        // 64*SK
    int t = threadIdx.x;
    int nb = blockIdx.x * 64;

    int nK4 = K >> 2;
    if (in_f16) {
        const __half* xh = (const __half*)xin;
        for (int i = t; i < 64 * nK4; i += 256) {
            int row = i / nK4, c4 = i % nK4;
            int gr = nb + row; if (gr >= N) gr = N - 1;
            u64 v = ((const u64*)(xh + (size_t)gr * K))[c4];
            *(u64*)&xs[row * SK + c4 * 4] = v;
        }
    } else {
        const float* xf = (const float*)xin;
        for (int i = t; i < 64 * nK4; i += 256) {
            int row = i / nK4, c4 = i % nK4;
            int gr = nb + row; if (gr >= N) gr = N - 1;
            float4 v = ((const float4*)(xf + (size_t)gr * K))[c4];
            f16* p = &xs[row * SK + c4 * 4];
            p[0] = (f16)v.x; p[1] = (f16)v.y; p[2] = (f16)v.z; p[3] = (f16)v.w;
        }
    }
    for (int i = t; i < K * 64; i += 256) {
        int k = i >> 6, c = i & 63;
        wt[c * SK + k] = (f16)W[i];
    }
    __syncthreads();

    int wv = t >> 6, lane = t & 63;
    int m = lane & 15, quad = lane >> 4;
    int rowA = wv * 16 + m;

    f32x4 acc[4];
#pragma unroll
    for (int ct = 0; ct < 4; ++ct) acc[ct] = (f32x4){0.f, 0.f, 0.f, 0.f};

    for (int ks = 0; ks < (K >> 5); ++ks) {
        f16x8 a = *(const f16x8*)&xs[rowA * SK + ks * 32 + quad * 8];
#pragma unroll
        for (int ct = 0; ct < 4; ++ct) {
            f16x8 bf = *(const f16x8*)&wt[(ct * 16 + m) * SK + ks * 32 + quad * 8];
            acc[ct] = __builtin_amdgcn_mfma_f32_16x16x32_f16(a, bf, acc[ct], 0, 0, 0);
        }
    }

    __syncthreads();
    f16* ht = xs;
    const int HS = 72;
#pragma unroll
    for (int ct = 0; ct < 4; ++ct)
#pragma unroll
        for (int r = 0; r < 4; ++r) {
            int rl = wv * 16 + quad * 4 + r;
            ht[rl * HS + ct * 16 + m] = (f16)acc[ct][r];
        }
    __syncthreads();

    {
        int row = t >> 2, cb = (t & 3) * 16;
        int gr = nb + row;
        if (gr < N) {
            ulonglong2 v0 = *(const ulonglong2*)&ht[row * HS + cb];
            ulonglong2 v1 = *(const ulonglong2*)&ht[row * HS + cb + 8];
            *(ulonglong2*)(h + (size_t)gr * HD + cb) = v0;
            *(ulonglong2*)(h + (size_t)gr * HD + cb + 8) = v1;
        }
    }
    float ac = a_s[lane], adc = a_d[lane];
    for (int rr = 0; rr < 16; ++rr) {
        int row = wv * 16 + rr, gr = nb + row;
        float v = (float)ht[row * HS + lane];
        float vs = v * ac, vd = v * adc;
#pragma unroll
        for (int dd = 32; dd; dd >>= 1) {
            vs += __shfl_down(vs, dd, 64);
            vd += __shfl_down(vd, dd, 64);
        }
        if (lane == 0 && gr < N) { as_n[gr] = vs; ad_n[gr] = vd; }
    }
}

// ---------------- per-node aggregation: lane-parallel alpha + shuffle-broadcast FMA ----------------
__global__ void k_aggr(const __half* __restrict__ h, const float* __restrict__ as_n,
                       const float* __restrict__ ad_n, const int* __restrict__ row_ptr,
                       const u64* __restrict__ rec, int l,
                       const float* __restrict__ b, __half* __restrict__ x_out,
                       float* __restrict__ emb, int N, int first) {
    int wave = threadIdx.x >> 6, lane = threadIdx.x & 63;
    int n = blockIdx.x * 4 + wave;
    if (n >= N) return;
    int base = row_ptr[n], end = row_ptr[n + 1];
    float adv = ad_n[n];
    const int shift = 16 * (l + 1);
    float m = -INFINITY, d = 0.f, acc = 0.f;

    for (int c = base; c < end; c += 64) {
        int cnt = min(64, end - c);
        float a = -INFINITY;
        int s = 0;
        if (lane < cnt) {
            u64 r = rec[c + lane];
            s = (int)(r & 0xFFFFull);
            float aE = __half2float(__ushort_as_half((unsigned short)(r >> shift)));
            a = as_n[s] + adv + aE;
            a = (a > 0.f) ? a : 0.2f * a;
        }
        float mc = a;
#pragma unroll
        for (int dd = 32; dd; dd >>= 1) mc = fmaxf(mc, __shfl_xor(mc, dd, 64));
        float mn = fmaxf(m, mc);
        float w = (lane < cnt) ? __expf(a - mn) : 0.f;
        float dc = w;
#pragma unroll
        for (int dd = 32; dd; dd >>= 1) dc += __shfl_xor(dc, dd, 64);
        float sc = __expf(m - mn);
        d = d * sc + dc;
        acc = acc * sc;
        m = mn;
        int j = 0;
        for (; j + 7 < cnt; j += 8) {
            int sx[8]; float wx[8];
#pragma unroll
            for (int q = 0; q < 8; ++q) {
                sx[q] = __shfl(s, j + q, 64);
                wx[q] = __shfl(w, j + q, 64);
            }
            float hx[8];
#pragma unroll
            for (int q = 0; q < 8; ++q)
                hx[q] = __half2float(h[(size_t)sx[q] * HD + lane]);
#pragma unroll
            for (int q = 0; q < 8; ++q) acc += wx[q] * hx[q];
        }
        for (; j + 3 < cnt; j += 4) {
            int s0 = __shfl(s, j, 64), s1 = __shfl(s, j + 1, 64),
                s2 = __shfl(s, j + 2, 64), s3 = __shfl(s, j + 3, 64);
            float w0 = __shfl(w, j, 64), w1 = __shfl(w, j + 1, 64),
                  w2 = __shfl(w, j + 2, 64), w3 = __shfl(w, j + 3, 64);
            float h0 = __half2float(h[(size_t)s0 * HD + lane]);
            float h1 = __half2float(h[(size_t)s1 * HD + lane]);
            float h2 = __half2float(h[(size_t)s2 * HD + lane]);
            float h3 = __half2float(h[(size_t)s3 * HD + lane]);
            acc += w0 * h0; acc += w1 * h1; acc += w2 * h2; acc += w3 * h3;
        }
        for (; j < cnt; ++j) {
            int sj = __shfl(s, j, 64);
            float wj = __shfl(w, j, 64);
            acc += wj * __half2float(h[(size_t)sj * HD + lane]);
        }
    }

    float out = acc / (d + 1e-16f) + b[lane];
    float v = (out > 0.f) ? out : expm1f(out);
    x_out[(size_t)n * HD + lane] = __float2half(v);
    if (first) emb[(size_t)n * HD + lane] = v;
    else emb[(size_t)n * HD + lane] += v;
}

// ---------------- column sums of emb -> gacc (atomic) ----------------
__global__ void k_red(const float* __restrict__ emb, float* gacc, int N) {
    __shared__ float lds[256];
    int f = threadIdx.x & 63, w = threadIdx.x >> 6;
    float s = 0.f;
    for (int n = blockIdx.x * 4 + w; n < N; n += gridDim.x * 4)
        s += emb[(size_t)n * HD + f];
    lds[threadIdx.x] = s;
    __syncthreads();
    if (w == 0) {
        float v = lds[f] + lds[64 + f] + lds[128 + f] + lds[192 + f];
        atomicAdd(&gacc[f], v);
    }
}

__global__ void k_div(const float* __restrict__ gacc, float* out, int N) {
    int f = threadIdx.x;
    if (f < HD) out[(size_t)N * HD + f] = gacc[f] / (float)N;
}

extern "C" void kernel_launch(void* const* d_in, const int* in_sizes, int n_in,
                              void* d_out, int out_size, void* d_ws, size_t ws_size,
                              hipStream_t stream) {
    const float* x = (const float*)d_in[0];
    const int* ei = (const int*)d_in[1];
    const float* ea = (const float*)d_in[2];

    const int FIN = in_sizes[3] / HD;       // W1 is [F_IN, 64]
    const int N = in_sizes[0] / FIN;
    const int E = in_sizes[1] / 2;
    const int FE = in_sizes[2] / E;
    const int Ep = E + N;
    const int NBK = (N + 255) >> 8;         // dst buckets of 256 nodes
    const int NPRE = 512;                   // k_bucket blocks

    const float* W[3];  const float* as_[3]; const float* ad_[3];
    const float* We[3]; const float* ae_[3]; const float* bb[3];
    for (int l = 0; l < 3; ++l) {
        W[l]  = (const float*)d_in[3 + 6 * l + 0];
        as_[l] = (const float*)d_in[3 + 6 * l + 1];
        ad_[l] = (const float*)d_in[3 + 6 * l + 2];
        We[l] = (const float*)d_in[3 + 6 * l + 3];
        ae_[l] = (const float*)d_in[3 + 6 * l + 4];
        bb[l] = (const float*)d_in[3 + 6 * l + 5];
    }

    int gN = (N + 255) / 256;
    int ntiles = (E + 255) / 256;
    int chunk = (E + NPRE - 1) / NPRE;

    // ---- workspace layout (bytes, 256-aligned) ----
    char* ws = (char*)d_ws;
    size_t off = 0;
    auto alloc = [&](size_t bytes) {
        void* p = ws + off;
        off += (bytes + 255) & ~(size_t)255;
        return p;
    };
    __half* h      = (__half*)alloc((size_t)N * HD * 2);
    __half* x_cur  = (__half*)alloc((size_t)N * HD * 2);
    float*  as_n   = (float*)alloc((size_t)N * 4);
    float*  ad_n   = (float*)alloc((size_t)N * 4);
    int*    cnt    = (int*)alloc((size_t)N * 4);
    int*    rowp   = (int*)alloc((size_t)(N + 1) * 4);
    int*    pre    = (int*)alloc((size_t)N * 4);
    int*    bsums  = (int*)alloc(256 * 4);
    int*    total  = (int*)alloc(4);
    int*    bfill  = (int*)alloc((size_t)MAXNBK * 16 * 4);  // padded (64B/bucket)
    int*    bbase  = (int*)alloc((size_t)(MAXNBK + 1) * 4);
    u64*    rec    = (u64*)alloc((size_t)Ep * 8);
    u64*    recE   = (u64*)alloc((size_t)E * 8);
    u64*    binned = (u64*)alloc((size_t)E * 8);
    unsigned char* bdstl = (unsigned char*)alloc((size_t)E);
    float*  partials = (float*)alloc((size_t)ntiles * 16 * 4);
    float*  sE     = (float*)alloc(3 * 4);
    float*  gacc   = (float*)alloc(HD * 4);
    (void)ws_size; (void)n_in; (void)out_size;

    float* emb = (float*)d_out;

    k_init<<<gN, 256, 0, stream>>>(cnt, gacc, N);
    size_t pre_lds = (size_t)(256 * (FE + 1) + 3 * FE + 256 * 4) * 4;
    k_pre<<<ntiles, 256, pre_lds, stream>>>(ei, ea, We[0], ae_[0], We[1], ae_[1],
                                            We[2], ae_[2], E, FE, cnt, recE, partials);
    k_scanA<<<gN, 256, 0, stream>>>(cnt, pre, bsums, N);
    k_scanB<<<1, 256, 0, stream>>>(bsums, gN, total);
    k_u2<<<1, 256, 0, stream>>>(partials, ntiles, We[0], ae_[0], We[1], ae_[1],
                                We[2], ae_[2], sE, FE, 1.0f / (float)E,
                                bsums, bfill, bbase, NBK, N, E);
    k_scanC<<<gN, 256, 0, stream>>>(pre, bsums, total, rowp, rec, sE, N);
    k_bucket<<<NPRE, 256, 0, stream>>>(ei, recE, E, chunk, bfill, binned, bdstl, NBK);
    k_sort<<<NBK, 256, 0, stream>>>(bbase, rowp, binned, bdstl, rec, N);

    for (int l = 0; l < 3; ++l) {
        const void* xin = (l == 0) ? (const void*)x : (const void*)x_cur;
        int in_f16 = (l == 0) ? 0 : 1;
        int K = (l == 0) ? FIN : HD;
        size_t ldsz = (size_t)(2 * 64 * (K + 8)) * 2;  // xs + wt, f16
        k_gemm<<<(N + 63) / 64, 256, ldsz, stream>>>(xin, in_f16, W[l], as_[l], ad_[l],
                                                     h, as_n, ad_n, N, K);
        k_aggr<<<(N + 3) / 4, 256, 0, stream>>>(h, as_n, ad_n, rowp, rec, l,
                                                bb[l], x_cur, emb, N, (l == 0) ? 1 : 0);
    }

    k_red<<<256, 256, 0, stream>>>(emb, gacc, N);
    k_div<<<1, 64, 0, stream>>>(gacc, emb, N);
}